// Round 1
// baseline (273.490 us; speedup 1.0000x reference)
//
#include <hip/hip_runtime.h>

// RawISPProcessing: demosaic (bilinear 2x, flips are no-ops) + folded
// (x2 * flip * awb^T * ccm^T * flip) 3x3 matrix + clip + gamma 1/2.2.
// One thread per 2x2 output quad, processes both pred and gt.

#define GAMMA_INV 0.45454545454545453f
#define EPS_CLIP 1e-8f

// up2 bilinear (half-pixel centers, edge-clamped) evaluated at the 2x2 output
// quad corresponding to source pixel (j,i). Needs 3x3 source neighborhood.
__device__ __forceinline__ float4 up2_quad(const float* __restrict__ p,
                                           int jm, int j, int jp,
                                           int im, int i, int ip) {
  const int W = 512;
  const float* r0 = p + jm * W;
  const float* r1 = p + j  * W;
  const float* r2 = p + jp * W;
  float a0 = r0[im], a1 = r0[i], a2 = r0[ip];
  float b0 = r1[im], b1 = r1[i], b2 = r1[ip];
  float c0 = r2[im], c1 = r2[i], c2 = r2[ip];
  // even output row: 0.25*row(j-1) + 0.75*row(j); odd: 0.75*row(j)+0.25*row(j+1)
  float e0 = 0.25f * a0 + 0.75f * b0;
  float e1 = 0.25f * a1 + 0.75f * b1;
  float e2 = 0.25f * a2 + 0.75f * b2;
  float o0 = 0.75f * b0 + 0.25f * c0;
  float o1 = 0.75f * b1 + 0.25f * c1;
  float o2 = 0.75f * b2 + 0.25f * c2;
  float4 r;
  r.x = 0.25f * e0 + 0.75f * e1;  // (even row, even col)
  r.y = 0.75f * e1 + 0.25f * e2;  // (even row, odd col)
  r.z = 0.25f * o0 + 0.75f * o1;  // (odd row, even col)
  r.w = 0.75f * o1 + 0.25f * o2;  // (odd row, odd col)
  return r;
}

__device__ __forceinline__ float gamma_enc(float v) {
  v = fmaxf(v, EPS_CLIP);
  return exp2f(GAMMA_INV * log2f(v));
}

__global__ __launch_bounds__(256) void isp_kernel(
    const float* __restrict__ pred, const float* __restrict__ gt,
    const float* __restrict__ awb, const float* __restrict__ ccm,
    float* __restrict__ out) {
  constexpr int H = 512, W = 512;
  constexpr int HW = H * W;                       // 262144
  constexpr long long OUT_IMG = 8LL * 3 * 1024 * 1024;  // 25165824 floats per image

  int idx = blockIdx.x * blockDim.x + threadIdx.x;  // 0 .. 8*512*512-1
  int i = idx & (W - 1);
  int j = (idx >> 9) & (H - 1);
  int b = idx >> 18;

  // Folded color matrix: out[k] = 2 * sum_e v[e] * sum_c A[2-e][c]*C[c][2-k]
  const float* A  = awb + b * 9;
  const float* Cm = ccm + b * 9;
  float M[3][3];
#pragma unroll
  for (int k = 0; k < 3; ++k) {
#pragma unroll
    for (int e = 0; e < 3; ++e) {
      int ar = (2 - e) * 3;
      int cc = 2 - k;
      M[k][e] = 2.0f * (A[ar + 0] * Cm[0 + cc] +
                        A[ar + 1] * Cm[3 + cc] +
                        A[ar + 2] * Cm[6 + cc]);
    }
  }

  int jm = (j > 0) ? j - 1 : 0;
  int jp = (j < H - 1) ? j + 1 : H - 1;
  int im = (i > 0) ? i - 1 : 0;
  int ip = (i < W - 1) ? i + 1 : W - 1;

  int oy = 2 * j, ox = 2 * i;

#pragma unroll
  for (int img = 0; img < 2; ++img) {
    const float* src = (img == 0 ? pred : gt) + (long long)b * 4 * HW;
    float* dst = out + (long long)img * OUT_IMG;

    float4 R  = up2_quad(src + 0 * HW, jm, j, jp, im, i, ip);
    float4 Gr = up2_quad(src + 1 * HW, jm, j, jp, im, i, ip);
    float4 Gb = up2_quad(src + 2 * HW, jm, j, jp, im, i, ip);
    float4 Bl = up2_quad(src + 3 * HW, jm, j, jp, im, i, ip);

    // Green per quad-parity (pixel_unshuffle/stack/shuffle collapse):
    float r[4]  = {R.x, R.y, R.z, R.w};
    float g[4]  = {0.5f * (Gr.x + Gb.x), Gr.y, Gb.z, 0.5f * (Gr.w + Gb.w)};
    float bl[4] = {Bl.x, Bl.y, Bl.z, Bl.w};

    float o[3][4];
#pragma unroll
    for (int px = 0; px < 4; ++px) {
#pragma unroll
      for (int k = 0; k < 3; ++k) {
        float v = M[k][0] * r[px] + M[k][1] * g[px] + M[k][2] * bl[px];
        o[k][px] = gamma_enc(v);
      }
    }

#pragma unroll
    for (int k = 0; k < 3; ++k) {
      long long obase = ((long long)(b * 3 + k) * 1024 + oy) * 1024 + ox;
      float2 top = make_float2(o[k][0], o[k][1]);
      float2 bot = make_float2(o[k][2], o[k][3]);
      *reinterpret_cast<float2*>(dst + obase) = top;
      *reinterpret_cast<float2*>(dst + obase + 1024) = bot;
    }
  }
}

extern "C" void kernel_launch(void* const* d_in, const int* in_sizes, int n_in,
                              void* d_out, int out_size, void* d_ws, size_t ws_size,
                              hipStream_t stream) {
  const float* pred = (const float*)d_in[0];
  const float* gt   = (const float*)d_in[1];
  const float* awb  = (const float*)d_in[2];
  const float* ccm  = (const float*)d_in[3];
  // d_in[4] = rgb_gain: unused by the reference.
  float* out = (float*)d_out;

  const int total = 8 * 512 * 512;  // one thread per 2x2 output quad per batch
  dim3 block(256);
  dim3 grid(total / 256);
  isp_kernel<<<grid, block, 0, stream>>>(pred, gt, awb, ccm, out);
}

// Round 2
// 271.537 us; speedup vs baseline: 1.0072x; 1.0072x over previous
//
#include <hip/hip_runtime.h>

// RawISPProcessing: demosaic (bilinear 2x; all flips are no-ops under the
// symmetric half-pixel grid) + folded (x2 * chflip * awb^T * ccm^T * chflip)
// 3x3 matrix + clip + gamma 1/2.2.
//
// R2: 4 source pixels per thread via aligned float4 row loads + 2 scalar halo
// loads (9 VMEM inst / 4 px / channel vs 72 scalar loads per px in R1).
// pred vs gt split across threads (img bit) to bound register pressure.

#define GAMMA_INV 0.45454545454545453f
#define EPS_CLIP 1e-8f

__device__ __forceinline__ float gamma_enc(float v) {
  v = fmaxf(v, EPS_CLIP);
  return exp2f(GAMMA_INV * __log2f(v));
}

// Load 6-wide row window [im, i..i+3, ip] for one channel row.
__device__ __forceinline__ void load_row(const float* __restrict__ row,
                                         int im, int i, int ip, float w[6]) {
  float4 v = *reinterpret_cast<const float4*>(row + i);
  w[0] = row[im];
  w[1] = v.x; w[2] = v.y; w[3] = v.z; w[4] = v.w;
  w[5] = row[ip];
}

// up2 for 4 consecutive source pixels of one channel -> top[8], bot[8].
__device__ __forceinline__ void up2_row4(const float* __restrict__ ch,
                                         int jm, int j, int jp,
                                         int im, int i, int ip,
                                         float top[8], float bot[8]) {
  const int W = 512;
  float w0[6], w1[6], w2[6];
  load_row(ch + jm * W, im, i, ip, w0);
  load_row(ch + j  * W, im, i, ip, w1);
  load_row(ch + jp * W, im, i, ip, w2);
  float e[6], o[6];
#pragma unroll
  for (int c = 0; c < 6; ++c) {
    e[c] = 0.25f * w0[c] + 0.75f * w1[c];  // even output row
    o[c] = 0.75f * w1[c] + 0.25f * w2[c];  // odd output row
  }
#pragma unroll
  for (int p = 0; p < 4; ++p) {
    int wp = p + 1;
    top[2 * p]     = 0.25f * e[wp - 1] + 0.75f * e[wp];
    top[2 * p + 1] = 0.75f * e[wp]     + 0.25f * e[wp + 1];
    bot[2 * p]     = 0.25f * o[wp - 1] + 0.75f * o[wp];
    bot[2 * p + 1] = 0.75f * o[wp]     + 0.25f * o[wp + 1];
  }
}

__global__ __launch_bounds__(256) void isp_kernel(
    const float* __restrict__ pred, const float* __restrict__ gt,
    const float* __restrict__ awb, const float* __restrict__ ccm,
    float* __restrict__ out) {
  constexpr int H = 512, W = 512;
  constexpr int HW = H * W;
  constexpr long long OUT_IMG = 8LL * 3 * 1024 * 1024;

  int idx = blockIdx.x * blockDim.x + threadIdx.x;  // 2*8*512*128 threads
  int t   = idx & 127;          // i-group: src cols [4t, 4t+3]
  int j   = (idx >> 7) & 511;   // src row
  int b   = (idx >> 16) & 7;    // batch
  int img = idx >> 19;          // 0=pred, 1=gt

  // Folded color matrix: out[k] = 2 * sum_e v[e] * sum_c awb[2-e][c]*ccm[c][2-k]
  const float* A  = awb + b * 9;
  const float* Cm = ccm + b * 9;
  float M[3][3];
#pragma unroll
  for (int k = 0; k < 3; ++k) {
#pragma unroll
    for (int e = 0; e < 3; ++e) {
      int ar = (2 - e) * 3;
      int cc = 2 - k;
      M[k][e] = 2.0f * (A[ar + 0] * Cm[0 + cc] +
                        A[ar + 1] * Cm[3 + cc] +
                        A[ar + 2] * Cm[6 + cc]);
    }
  }

  int i  = 4 * t;
  int jm = (j > 0) ? j - 1 : 0;
  int jp = (j < H - 1) ? j + 1 : H - 1;
  int im = (i > 0) ? i - 1 : 0;
  int ip = (i + 4 < W) ? i + 4 : W - 1;

  const float* src = (img ? gt : pred) + (long long)b * 4 * HW;

  float rT[8], rB[8], gT[8], gB[8], bT[8], bB[8];
  float tT[8], tB[8];

  up2_row4(src + 0 * HW, jm, j, jp, im, i, ip, rT, rB);   // red
  up2_row4(src + 1 * HW, jm, j, jp, im, i, ip, gT, gB);   // Gr
  up2_row4(src + 2 * HW, jm, j, jp, im, i, ip, tT, tB);   // Gb
  // Green quad-parity combine: (ee)=avg, (eo)=Gr, (oe)=Gb, (oo)=avg.
#pragma unroll
  for (int p = 0; p < 4; ++p) {
    gT[2 * p]     = 0.5f * (gT[2 * p] + tT[2 * p]);
    /* gT[2p+1] stays Gr */
    gB[2 * p]     = tB[2 * p];
    gB[2 * p + 1] = 0.5f * (gB[2 * p + 1] + tB[2 * p + 1]);
  }
  up2_row4(src + 3 * HW, jm, j, jp, im, i, ip, bT, bB);   // blue

  int oy = 2 * j, ox = 8 * t;
  float* dst = out + (long long)img * OUT_IMG;

#pragma unroll
  for (int k = 0; k < 3; ++k) {
    float oT[8], oB[8];
#pragma unroll
    for (int p = 0; p < 8; ++p) {
      oT[p] = gamma_enc(M[k][0] * rT[p] + M[k][1] * gT[p] + M[k][2] * bT[p]);
      oB[p] = gamma_enc(M[k][0] * rB[p] + M[k][1] * gB[p] + M[k][2] * bB[p]);
    }
    long long obase = ((long long)(b * 3 + k) * 1024 + oy) * 1024 + ox;
    *reinterpret_cast<float4*>(dst + obase)          = make_float4(oT[0], oT[1], oT[2], oT[3]);
    *reinterpret_cast<float4*>(dst + obase + 4)      = make_float4(oT[4], oT[5], oT[6], oT[7]);
    *reinterpret_cast<float4*>(dst + obase + 1024)     = make_float4(oB[0], oB[1], oB[2], oB[3]);
    *reinterpret_cast<float4*>(dst + obase + 1028)     = make_float4(oB[4], oB[5], oB[6], oB[7]);
  }
}

extern "C" void kernel_launch(void* const* d_in, const int* in_sizes, int n_in,
                              void* d_out, int out_size, void* d_ws, size_t ws_size,
                              hipStream_t stream) {
  const float* pred = (const float*)d_in[0];
  const float* gt   = (const float*)d_in[1];
  const float* awb  = (const float*)d_in[2];
  const float* ccm  = (const float*)d_in[3];
  // d_in[4] = rgb_gain: unused by the reference.
  float* out = (float*)d_out;

  const int total = 2 * 8 * 512 * 128;  // img * batch * rows * col-groups
  dim3 block(256);
  dim3 grid(total / 256);
  isp_kernel<<<grid, block, 0, stream>>>(pred, gt, awb, ccm, out);
}